// Round 2
// baseline (252.230 us; speedup 1.0000x reference)
//
#include <hip/hip_runtime.h>
#include <stdint.h>

#define SEQ   4096
#define EMB   1024
#define NHEAD 8
#define HD    128
#define WIN   256
#define MROWS 8192   // SEQ*B
#define NCOLS 3072   // 3*EMB

typedef unsigned short u16;
typedef __bf16 v8bf  __attribute__((ext_vector_type(8)));
typedef float  v4f   __attribute__((ext_vector_type(4)));
typedef u16    v8u16 __attribute__((ext_vector_type(8)));

__device__ __forceinline__ u16 f2bf(float f) {
  uint32_t u = __builtin_bit_cast(uint32_t, f);
  u += 0x7FFFu + ((u >> 16) & 1u);
  return (u16)(u >> 16);
}
__device__ __forceinline__ void gl_lds16(const u16* g, u16* l) {
  __builtin_amdgcn_global_load_lds((const __attribute__((address_space(1))) void*)g,
                                   (__attribute__((address_space(3))) void*)l,
                                   16, 0, 0);
}

// ---------------------------------------------------------------------------
// f32 -> bf16 conversion: val (8.4M) and Wq/Wk/Wv (1M each) into workspace.
// ---------------------------------------------------------------------------
__global__ __launch_bounds__(256)
void cvt_f32_bf16(const float* __restrict__ val,
                  const float* __restrict__ Wq,
                  const float* __restrict__ Wk,
                  const float* __restrict__ Wv,
                  u16* __restrict__ valbf, u16* __restrict__ Wbf)
{
  const int seg = blockIdx.y;
  const float* src; u16* dst; int nblk;
  if (seg == 0)      { src = val; dst = valbf;              nblk = 4096; }
  else if (seg == 1) { src = Wq;  dst = Wbf;                nblk = 512;  }
  else if (seg == 2) { src = Wk;  dst = Wbf + (1u << 20);   nblk = 512;  }
  else               { src = Wv;  dst = Wbf + (2u << 20);   nblk = 512;  }
  if ((int)blockIdx.x >= nblk) return;
  const int t = blockIdx.x * 256 + threadIdx.x;   // 8 elems per thread
  float4 a = ((const float4*)src)[2 * t];
  float4 b = ((const float4*)src)[2 * t + 1];
  v8u16 o;
  o[0] = f2bf(a.x); o[1] = f2bf(a.y); o[2] = f2bf(a.z); o[3] = f2bf(a.w);
  o[4] = f2bf(b.x); o[5] = f2bf(b.y); o[6] = f2bf(b.z); o[7] = f2bf(b.w);
  ((v8u16*)dst)[t] = o;
}

// ---------------------------------------------------------------------------
// Fused QKV GEMM: C[a2][n] = sum_k A[a2][k] * W[n][k] (+bias, *scale for Q)
// A row a2 (attention order: a2 = b'*4096+s') gathered from val row
// grow = (a&4095)*2 + (a>>12), a = 2*(a2&4095) + (a2>>12).
// Tile 128x128, BK=64, 4 waves (2x2), global_load_lds w/ XOR chunk swizzle.
// ---------------------------------------------------------------------------
__global__ __launch_bounds__(256, 3)
void qkv_gemm(const u16* __restrict__ valbf, const u16* __restrict__ Wbf,
              const float* __restrict__ bq, const float* __restrict__ bk,
              const float* __restrict__ bv,
              u16* __restrict__ Qb, u16* __restrict__ Kb, u16* __restrict__ Vb)
{
  __shared__ __align__(16) u16 As[128 * 64];
  __shared__ __align__(16) u16 Bs[128 * 64];

  const int tid  = threadIdx.x;
  const int lane = tid & 63;
  const int w    = tid >> 6;
  const int quad = lane >> 4;
  const int lq   = lane & 15;
  const int wm   = w >> 1, wn = w & 1;

  const int bn = blockIdx.x;   // 0..23 (N tiles)
  const int bm = blockIdx.y;   // 0..63 (M tiles)

  const int seg = bn >> 3;     // 0=Q 1=K 2=V
  const u16*   Wsel = Wbf + (size_t)seg * EMB * EMB;
  const float* bsel = seg == 0 ? bq : (seg == 1 ? bk : bv);
  u16*         Osel = seg == 0 ? Qb : (seg == 1 ? Kb : Vb);
  const int nseg0 = (bn & 7) * 128;

  // per-call staging source pointers (chunk = 8 bf16 = 16B)
  const u16* arow[4];
  const u16* brow[4];
#pragma unroll
  for (int call = 0; call < 4; ++call) {
    int c  = call * 256 + w * 64 + lane;   // LDS chunk index
    int m  = c >> 3;
    int qs = c & 7;
    int q  = qs ^ (m & 7);                 // swizzle: slot qs holds global chunk q
    int a2 = bm * 128 + m;
    int aa = 2 * (a2 & 4095) + (a2 >> 12);
    int grow = (aa & 4095) * 2 + (aa >> 12);
    arow[call] = valbf + (size_t)grow * EMB + q * 8;
    int n = nseg0 + m;
    brow[call] = Wsel + (size_t)n * EMB + q * 8;
  }

  v4f acc[4][4];
#pragma unroll
  for (int mt = 0; mt < 4; ++mt)
#pragma unroll
    for (int nt = 0; nt < 4; ++nt) acc[mt][nt] = (v4f){0.f, 0.f, 0.f, 0.f};

#pragma unroll 1
  for (int kt = 0; kt < 16; ++kt) {
    const int k0 = kt * 64;
    __syncthreads();
#pragma unroll
    for (int call = 0; call < 4; ++call) {
      gl_lds16(arow[call] + k0, &As[(call * 256 + w * 64) * 8]);
      gl_lds16(brow[call] + k0, &Bs[(call * 256 + w * 64) * 8]);
    }
    __syncthreads();
#pragma unroll
    for (int ks = 0; ks < 2; ++ks) {
      v8bf afr[4], bfr[4];
      const int qa = ks * 4 + quad;
#pragma unroll
      for (int mt = 0; mt < 4; ++mt) {
        int m = wm * 64 + mt * 16 + lq;
        int chunk = m * 8 + (qa ^ (m & 7));
        afr[mt] = *(const v8bf*)&As[chunk * 8];
      }
#pragma unroll
      for (int nt = 0; nt < 4; ++nt) {
        int n = wn * 64 + nt * 16 + lq;
        int chunk = n * 8 + (qa ^ (n & 7));
        bfr[nt] = *(const v8bf*)&Bs[chunk * 8];
      }
#pragma unroll
      for (int mt = 0; mt < 4; ++mt)
#pragma unroll
        for (int nt = 0; nt < 4; ++nt)
          acc[mt][nt] = __builtin_amdgcn_mfma_f32_16x16x32_bf16(afr[mt], bfr[nt], acc[mt][nt], 0, 0, 0);
    }
  }

  // epilogue: bias (+scale for Q), bf16, store. C row = quad*4+reg, col = lq.
  const float scale = 0.08838834764831845f;  // 1/sqrt(128)
  float bias[4];
#pragma unroll
  for (int nt = 0; nt < 4; ++nt)
    bias[nt] = bsel[nseg0 + wn * 64 + nt * 16 + lq];
#pragma unroll
  for (int mt = 0; mt < 4; ++mt) {
    int rbase = bm * 128 + wm * 64 + mt * 16 + quad * 4;
#pragma unroll
    for (int nt = 0; nt < 4; ++nt) {
      int ncol = nseg0 + wn * 64 + nt * 16 + lq;
#pragma unroll
      for (int r = 0; r < 4; ++r) {
        float v = acc[mt][nt][r] + bias[nt];
        if (seg == 0) v *= scale;
        Osel[(size_t)(rbase + r) * EMB + ncol] = f2bf(v);
      }
    }
  }
}

// ---------------------------------------------------------------------------
// Banded attention, flash-style. Grid: (64 q-tiles, 16 = b'*8+h). 4 waves,
// wave w owns query rows [q0+16w, q0+16w+16). Band |j-s'|<=256; out-of-range
// positions contribute exp(0) to denominator only (reference zero-padding).
// ---------------------------------------------------------------------------
__global__ __launch_bounds__(256, 2)
void local_attn(const u16* __restrict__ Qb, const u16* __restrict__ Kb,
                const u16* __restrict__ Vb, float* __restrict__ out)
{
  __shared__ __align__(16) u16 sVT[128 * 72];  // V^T tile: [d][j], stride 72
  __shared__ __align__(16) u16 sP[64 * 72];    // P tile: [i][j], stride 72

  const int tid  = threadIdx.x;
  const int lane = tid & 63;
  const int w    = tid >> 6;
  const int quad = lane >> 4;
  const int lq   = lane & 15;

  const int q0 = blockIdx.x * 64;
  const int bp = blockIdx.y >> 3;   // b'
  const int h  = blockIdx.y & 7;
  const size_t rowbase = (size_t)bp * SEQ;

  // Q A-fragments (pre-scaled in GEMM), 4 k-steps over D=128
  v8bf qf[4];
  {
    const u16* qrow = Qb + (rowbase + q0 + w * 16 + lq) * EMB + h * HD;
#pragma unroll
    for (int ks = 0; ks < 4; ++ks)
      qf[ks] = *(const v8bf*)(qrow + ks * 32 + quad * 8);
  }

  v4f oacc[8];
#pragma unroll
  for (int dt = 0; dt < 8; ++dt) oacc[dt] = (v4f){0.f, 0.f, 0.f, 0.f};
  float mrow[4], lrow[4];
#pragma unroll
  for (int r = 0; r < 4; ++r) { mrow[r] = -1e30f; lrow[r] = 0.f; }

  const int jlo = (q0 - WIN > 0) ? q0 - WIN : 0;
  const int jhi = (q0 + 64 + WIN < SEQ) ? q0 + 64 + WIN : SEQ;

  for (int kb = jlo; kb < jhi; kb += 64) {
    __syncthreads();

    // --- stage V^T: VT[d][j-kb] (packed dword writes) ---
    {
      const int jp = tid & 31;          // j pair
      const int dc = tid >> 5;          // 0..7
      const int j0 = kb + jp * 2;
      uint32_t* vt = (uint32_t*)sVT;
#pragma unroll
      for (int pass = 0; pass < 2; ++pass) {
        const int d0 = dc * 8 + pass * 64;
        const u16* v0p = Vb + (rowbase + j0) * EMB + h * HD + d0;
        v8u16 va = *(const v8u16*)v0p;
        v8u16 vb = *(const v8u16*)(v0p + EMB);
#pragma unroll
        for (int i = 0; i < 8; ++i)
          vt[(d0 + i) * 36 + jp] = (uint32_t)va[i] | ((uint32_t)vb[i] << 16);
      }
    }

    // --- S = Q K^T (K B-frags straight from global) ---
    v4f sfr[4];
#pragma unroll
    for (int nt = 0; nt < 4; ++nt) sfr[nt] = (v4f){0.f, 0.f, 0.f, 0.f};
#pragma unroll
    for (int ks = 0; ks < 4; ++ks) {
      v8bf kf[4];
#pragma unroll
      for (int nt = 0; nt < 4; ++nt) {
        const u16* krow = Kb + (rowbase + kb + nt * 16 + lq) * EMB + h * HD;
        kf[nt] = *(const v8bf*)(krow + ks * 32 + quad * 8);
      }
#pragma unroll
      for (int nt = 0; nt < 4; ++nt)
        sfr[nt] = __builtin_amdgcn_mfma_f32_16x16x32_bf16(qf[ks], kf[nt], sfr[nt], 0, 0, 0);
    }

    // --- band mask ---
#pragma unroll
    for (int nt = 0; nt < 4; ++nt) {
      int j = kb + nt * 16 + lq;
#pragma unroll
      for (int r = 0; r < 4; ++r) {
        int sr = q0 + w * 16 + quad * 4 + r;
        int d = j - sr;
        if (d > WIN || d < -WIN) sfr[nt][r] = -1e30f;
      }
    }

    // --- online softmax (row stats live on the 16 lanes of each quad) ---
    float alpha[4];
#pragma unroll
    for (int r = 0; r < 4; ++r) {
      float mx = fmaxf(fmaxf(sfr[0][r], sfr[1][r]), fmaxf(sfr[2][r], sfr[3][r]));
#pragma unroll
      for (int off = 1; off < 16; off <<= 1) mx = fmaxf(mx, __shfl_xor(mx, off));
      float mnew = fmaxf(mrow[r], mx);
      alpha[r] = __expf(mrow[r] - mnew);
      mrow[r] = mnew;
      float rs = 0.f;
#pragma unroll
      for (int nt = 0; nt < 4; ++nt) {
        float p = __expf(sfr[nt][r] - mnew);
        sfr[nt][r] = p;
        rs += p;
      }
#pragma unroll
      for (int off = 1; off < 16; off <<= 1) rs += __shfl_xor(rs, off);
      lrow[r] = lrow[r] * alpha[r] + rs;
    }
#pragma unroll
    for (int dt = 0; dt < 8; ++dt)
#pragma unroll
      for (int r = 0; r < 4; ++r) oacc[dt][r] *= alpha[r];

    // --- P -> LDS (C-layout to A-layout round trip) ---
#pragma unroll
    for (int nt = 0; nt < 4; ++nt)
#pragma unroll
      for (int r = 0; r < 4; ++r)
        sP[(w * 16 + quad * 4 + r) * 72 + nt * 16 + lq] = f2bf(sfr[nt][r]);

    __syncthreads();

    // --- O += P V ---
#pragma unroll
    for (int ks = 0; ks < 2; ++ks) {
      v8bf pf = *(const v8bf*)&sP[(w * 16 + lq) * 72 + ks * 32 + quad * 8];
#pragma unroll
      for (int dt = 0; dt < 8; ++dt) {
        v8bf vf = *(const v8bf*)&sVT[(dt * 16 + lq) * 72 + ks * 32 + quad * 8];
        oacc[dt] = __builtin_amdgcn_mfma_f32_16x16x32_bf16(pf, vf, oacc[dt], 0, 0, 0);
      }
    }
  }

  // --- zero-padding contribution (edges only) + finalize + scatter store ---
#pragma unroll
  for (int r = 0; r < 4; ++r) {
    int sr = q0 + w * 16 + quad * 4 + r;
    int npl = WIN - sr;             if (npl < 0) npl = 0;
    int npr = sr - (SEQ - 1 - WIN); if (npr < 0) npr = 0;
    int np = npl + npr;
    if (np > 0) {
      float mnew = fmaxf(mrow[r], 0.f);
      float al = __expf(mrow[r] - mnew);
      lrow[r] = lrow[r] * al + (float)np * __expf(-mnew);
#pragma unroll
      for (int dt = 0; dt < 8; ++dt) oacc[dt][r] *= al;
      mrow[r] = mnew;
    }
  }
#pragma unroll
  for (int dt = 0; dt < 8; ++dt) {
#pragma unroll
    for (int r = 0; r < 4; ++r) {
      int sr = q0 + w * 16 + quad * 4 + r;
      float o = oacc[dt][r] / lrow[r];
      out[(size_t)(2 * sr + bp) * EMB + h * HD + dt * 16 + lq] = o;
    }
  }
}

extern "C" void kernel_launch(void* const* d_in, const int* in_sizes, int n_in,
                              void* d_out, int out_size, void* d_ws, size_t ws_size,
                              hipStream_t stream) {
  const float* val = (const float*)d_in[0];
  const float* Wq  = (const float*)d_in[1];
  const float* bq  = (const float*)d_in[2];
  const float* Wk  = (const float*)d_in[3];
  const float* bk  = (const float*)d_in[4];
  const float* Wv  = (const float*)d_in[5];
  const float* bv  = (const float*)d_in[6];
  float* out = (float*)d_out;

  u16* valbf = (u16*)d_ws;                              // 8192*1024 bf16
  u16* Wbf   = valbf + (size_t)MROWS * EMB;             // 3*1024*1024 bf16
  u16* Qb    = Wbf + (size_t)3 * EMB * EMB;             // attention row order
  u16* Kb    = Qb + (size_t)MROWS * EMB;
  u16* Vb    = Kb + (size_t)MROWS * EMB;

  hipLaunchKernelGGL(cvt_f32_bf16, dim3(4096, 4), dim3(256), 0, stream,
                     val, Wq, Wk, Wv, valbf, Wbf);
  hipLaunchKernelGGL(qkv_gemm, dim3(24, 64), dim3(256), 0, stream,
                     valbf, Wbf, bq, bk, bv, Qb, Kb, Vb);
  hipLaunchKernelGGL(local_attn, dim3(64, 16), dim3(256), 0, stream,
                     Qb, Kb, Vb, out);
}

// Round 3
// 233.965 us; speedup vs baseline: 1.0781x; 1.0781x over previous
//
#include <hip/hip_runtime.h>
#include <stdint.h>

#define SEQ   4096
#define EMB   1024
#define HD    128
#define WIN   256
#define MROWS 8192   // SEQ*B

typedef unsigned short u16;
typedef unsigned long long u64;
typedef __bf16 v8bf  __attribute__((ext_vector_type(8)));
typedef float  v4f   __attribute__((ext_vector_type(4)));
typedef u16    v8u16 __attribute__((ext_vector_type(8)));

__device__ __forceinline__ u16 f2bf(float f) {
  uint32_t u = __builtin_bit_cast(uint32_t, f);
  u += 0x7FFFu + ((u >> 16) & 1u);
  return (u16)(u >> 16);
}
__device__ __forceinline__ void gl_lds16(const u16* g, u16* l) {
  __builtin_amdgcn_global_load_lds((const __attribute__((address_space(1))) void*)g,
                                   (__attribute__((address_space(3))) void*)l,
                                   16, 0, 0);
}

// ---------------------------------------------------------------------------
// f32 -> bf16 conversion: val (8.4M) and Wq/Wk/Wv (1M each) into workspace.
// ---------------------------------------------------------------------------
__global__ __launch_bounds__(256)
void cvt_f32_bf16(const float* __restrict__ val,
                  const float* __restrict__ Wq,
                  const float* __restrict__ Wk,
                  const float* __restrict__ Wv,
                  u16* __restrict__ valbf, u16* __restrict__ Wbf)
{
  const int seg = blockIdx.y;
  const float* src; u16* dst; int nblk;
  if (seg == 0)      { src = val; dst = valbf;              nblk = 4096; }
  else if (seg == 1) { src = Wq;  dst = Wbf;                nblk = 512;  }
  else if (seg == 2) { src = Wk;  dst = Wbf + (1u << 20);   nblk = 512;  }
  else               { src = Wv;  dst = Wbf + (2u << 20);   nblk = 512;  }
  if ((int)blockIdx.x >= nblk) return;
  const int t = blockIdx.x * 256 + threadIdx.x;   // 8 elems per thread
  float4 a = ((const float4*)src)[2 * t];
  float4 b = ((const float4*)src)[2 * t + 1];
  v8u16 o;
  o[0] = f2bf(a.x); o[1] = f2bf(a.y); o[2] = f2bf(a.z); o[3] = f2bf(a.w);
  o[4] = f2bf(b.x); o[5] = f2bf(b.y); o[6] = f2bf(b.z); o[7] = f2bf(b.w);
  ((v8u16*)dst)[t] = o;
}

// ---------------------------------------------------------------------------
// Fused QKV GEMM. Q/K stored row-major (attention order); V stored TRANSPOSED
// as VT[(b*8+h)*128 + d][s] (packed 8B scattered stores; L2 write-combines).
// ---------------------------------------------------------------------------
__global__ __launch_bounds__(256, 3)
void qkv_gemm(const u16* __restrict__ valbf, const u16* __restrict__ Wbf,
              const float* __restrict__ bq, const float* __restrict__ bk,
              const float* __restrict__ bv,
              u16* __restrict__ Qb, u16* __restrict__ Kb, u16* __restrict__ VTg)
{
  __shared__ __align__(16) u16 As[128 * 64];
  __shared__ __align__(16) u16 Bs[128 * 64];

  const int tid  = threadIdx.x;
  const int lane = tid & 63;
  const int w    = tid >> 6;
  const int quad = lane >> 4;
  const int lq   = lane & 15;
  const int wm   = w >> 1, wn = w & 1;

  const int bn = blockIdx.x;   // 0..23
  const int bm = blockIdx.y;   // 0..63

  const int seg = bn >> 3;     // 0=Q 1=K 2=V
  const u16*   Wsel = Wbf + (size_t)seg * EMB * EMB;
  const float* bsel = seg == 0 ? bq : (seg == 1 ? bk : bv);
  const int nseg0 = (bn & 7) * 128;

  const u16* arow[4];
  const u16* brow[4];
#pragma unroll
  for (int call = 0; call < 4; ++call) {
    int c  = call * 256 + w * 64 + lane;
    int m  = c >> 3;
    int qs = c & 7;
    int q  = qs ^ (m & 7);
    int a2 = bm * 128 + m;
    int aa = 2 * (a2 & 4095) + (a2 >> 12);
    int grow = (aa & 4095) * 2 + (aa >> 12);
    arow[call] = valbf + (size_t)grow * EMB + q * 8;
    int n = nseg0 + m;
    brow[call] = Wsel + (size_t)n * EMB + q * 8;
  }

  v4f acc[4][4];
#pragma unroll
  for (int mt = 0; mt < 4; ++mt)
#pragma unroll
    for (int nt = 0; nt < 4; ++nt) acc[mt][nt] = (v4f){0.f, 0.f, 0.f, 0.f};

#pragma unroll 1
  for (int kt = 0; kt < 16; ++kt) {
    const int k0 = kt * 64;
    __syncthreads();
#pragma unroll
    for (int call = 0; call < 4; ++call) {
      gl_lds16(arow[call] + k0, &As[(call * 256 + w * 64) * 8]);
      gl_lds16(brow[call] + k0, &Bs[(call * 256 + w * 64) * 8]);
    }
    __syncthreads();
#pragma unroll
    for (int ks = 0; ks < 2; ++ks) {
      v8bf afr[4], bfr[4];
      const int qa = ks * 4 + quad;
#pragma unroll
      for (int mt = 0; mt < 4; ++mt) {
        int m = wm * 64 + mt * 16 + lq;
        afr[mt] = *(const v8bf*)&As[(m * 8 + (qa ^ (m & 7))) * 8];
      }
#pragma unroll
      for (int nt = 0; nt < 4; ++nt) {
        int n = wn * 64 + nt * 16 + lq;
        bfr[nt] = *(const v8bf*)&Bs[(n * 8 + (qa ^ (n & 7))) * 8];
      }
#pragma unroll
      for (int mt = 0; mt < 4; ++mt)
#pragma unroll
        for (int nt = 0; nt < 4; ++nt)
          acc[mt][nt] = __builtin_amdgcn_mfma_f32_16x16x32_bf16(afr[mt], bfr[nt], acc[mt][nt], 0, 0, 0);
    }
  }

  const float scale = 0.08838834764831845f;  // 1/sqrt(128)
  float bias[4];
#pragma unroll
  for (int nt = 0; nt < 4; ++nt)
    bias[nt] = bsel[nseg0 + wn * 64 + nt * 16 + lq];

  if (seg == 2) {
    // V: store transposed, 4 m-consecutive values packed per 8B store
    const int h  = bn & 7;
    const int bp = bm >> 5;
    const int s0 = (bm & 31) * 128;
#pragma unroll
    for (int mt = 0; mt < 4; ++mt) {
      int mb = wm * 64 + mt * 16 + quad * 4;
#pragma unroll
      for (int nt = 0; nt < 4; ++nt) {
        int n = wn * 64 + nt * 16 + lq;   // = d
        u64 pk = 0;
#pragma unroll
        for (int r = 0; r < 4; ++r)
          pk |= (u64)f2bf(acc[mt][nt][r] + bias[nt]) << (16 * r);
        *(u64*)&VTg[((size_t)(bp * 8 + h) * HD + n) * SEQ + s0 + mb] = pk;
      }
    }
  } else {
    u16* Osel = (seg == 0) ? Qb : Kb;
#pragma unroll
    for (int mt = 0; mt < 4; ++mt) {
      int rbase = bm * 128 + wm * 64 + mt * 16 + quad * 4;
#pragma unroll
      for (int nt = 0; nt < 4; ++nt) {
        int ncol = nseg0 + wn * 64 + nt * 16 + lq;
#pragma unroll
        for (int r = 0; r < 4; ++r) {
          float v = acc[mt][nt][r] + bias[nt];
          if (seg == 0) v *= scale;
          Osel[(size_t)(rbase + r) * EMB + ncol] = f2bf(v);
        }
      }
    }
  }
}

// ---------------------------------------------------------------------------
// Banded attention. Zero-shift softmax (scores are O(1); exp(s) safe in fp32,
// padding = exp(0) = 1 added to denominator at the end). V^T tiles staged by
// async global_load_lds, double-buffered, XOR-swizzled; K fragments register-
// pipelined one key-block ahead. One barrier per key block. sP is wave-private.
// Grid (bh=16, qtile=64): all qtiles of one (b,h) share an XCD (L2 reuse).
// ---------------------------------------------------------------------------
__global__ __launch_bounds__(256, 2)
void local_attn(const u16* __restrict__ Qb, const u16* __restrict__ Kb,
                const u16* __restrict__ VTg, float* __restrict__ out)
{
  __shared__ __align__(16) u16 sVT[2][128 * 64];  // swizzled V^T tiles
  __shared__ __align__(16) u16 sP[64 * 72];       // P, wave-private rows

  const int tid  = threadIdx.x;
  const int lane = tid & 63;
  const int w    = tid >> 6;
  const int quad = lane >> 4;
  const int lq   = lane & 15;

  const int bh = blockIdx.x;        // b'*8 + h
  const int q0 = blockIdx.y * 64;
  const int bp = bh >> 3;
  const int h  = bh & 7;
  const size_t rowbase = (size_t)bp * SEQ;

  // Q A-fragments (pre-scaled in GEMM)
  v8bf qf[4];
  {
    const u16* qrow = Qb + (rowbase + q0 + w * 16 + lq) * EMB + h * HD;
#pragma unroll
    for (int ks = 0; ks < 4; ++ks)
      qf[ks] = *(const v8bf*)(qrow + ks * 32 + quad * 8);
  }

  v4f oacc[8];
#pragma unroll
  for (int dt = 0; dt < 8; ++dt) oacc[dt] = (v4f){0.f, 0.f, 0.f, 0.f};
  float ls[4] = {0.f, 0.f, 0.f, 0.f};

  const int jlo = (q0 - WIN > 0) ? q0 - WIN : 0;
  const int jhi = (q0 + 64 + WIN < SEQ) ? q0 + 64 + WIN : SEQ;
  const int nit = (jhi - jlo) >> 6;

  // async V^T tile stage: 1024 16B chunks, XOR-swizzled slots
  auto stageVT = [&](int kb, int p) {
#pragma unroll
    for (int call = 0; call < 4; ++call) {
      int c = (w * 4 + call) * 64 + lane;
      int d = c >> 3, slot = c & 7;
      int q = slot ^ (d & 7);
      gl_lds16(VTg + ((size_t)bh * HD + d) * SEQ + kb + q * 8,
               &sVT[p][(w * 4 + call) * 512]);
    }
  };

  // prologue: stage VT tile 0, preload K frags for iter 0
  stageVT(jlo, 0);
  v8bf kfc[4][4];
#pragma unroll
  for (int ks = 0; ks < 4; ++ks)
#pragma unroll
    for (int nt = 0; nt < 4; ++nt)
      kfc[ks][nt] = *(const v8bf*)(Kb + (rowbase + jlo + nt * 16 + lq) * EMB
                                   + h * HD + ks * 32 + quad * 8);

  for (int it = 0; it < nit; ++it) {
    const int p  = it & 1;
    const int kb = jlo + it * 64;
    __syncthreads();                         // drains DMA for buf p; frees buf p^1
    if (it + 1 < nit) stageVT(kb + 64, p ^ 1);
    const int kbn = (it + 1 < nit) ? kb + 64 : jlo;   // clamped prefetch target

    // --- S = Q K^T; refill kfc for next block right after each use ---
    v4f sfr[4];
#pragma unroll
    for (int nt = 0; nt < 4; ++nt) sfr[nt] = (v4f){0.f, 0.f, 0.f, 0.f};
#pragma unroll
    for (int ks = 0; ks < 4; ++ks) {
#pragma unroll
      for (int nt = 0; nt < 4; ++nt)
        sfr[nt] = __builtin_amdgcn_mfma_f32_16x16x32_bf16(qf[ks], kfc[ks][nt], sfr[nt], 0, 0, 0);
#pragma unroll
      for (int nt = 0; nt < 4; ++nt)
        kfc[ks][nt] = *(const v8bf*)(Kb + (rowbase + kbn + nt * 16 + lq) * EMB
                                     + h * HD + ks * 32 + quad * 8);
    }

    // --- mask + exp (no shift) + per-lane denominator + P to LDS ---
#pragma unroll
    for (int nt = 0; nt < 4; ++nt) {
      int j = kb + nt * 16 + lq;
#pragma unroll
      for (int r = 0; r < 4; ++r) {
        int sr = q0 + w * 16 + quad * 4 + r;
        int dd = j - sr;
        float pv = (dd <= WIN && dd >= -WIN) ? __expf(sfr[nt][r]) : 0.f;
        ls[r] += pv;
        sP[(w * 16 + quad * 4 + r) * 72 + nt * 16 + lq] = f2bf(pv);
      }
    }

    // --- O += P V (sP wave-private: no barrier) ---
#pragma unroll
    for (int ks = 0; ks < 2; ++ks) {
      v8bf pf = *(const v8bf*)&sP[(w * 16 + lq) * 72 + ks * 32 + quad * 8];
      const int qn = ks * 4 + quad;
#pragma unroll
      for (int dt = 0; dt < 8; ++dt) {
        int d = dt * 16 + lq;
        v8bf vf = *(const v8bf*)&sVT[p][(d * 8 + (qn ^ (d & 7))) * 8];
        oacc[dt] = __builtin_amdgcn_mfma_f32_16x16x32_bf16(pf, vf, oacc[dt], 0, 0, 0);
      }
    }
  }

  // --- finalize: reduce denominators, add zero-padding count, store ---
  float lrow[4];
#pragma unroll
  for (int r = 0; r < 4; ++r) {
    float t = ls[r];
#pragma unroll
    for (int off = 1; off < 16; off <<= 1) t += __shfl_xor(t, off);
    int sr = q0 + w * 16 + quad * 4 + r;
    int npl = WIN - sr;             if (npl < 0) npl = 0;
    int npr = sr - (SEQ - 1 - WIN); if (npr < 0) npr = 0;
    lrow[r] = t + (float)(npl + npr);
  }
#pragma unroll
  for (int dt = 0; dt < 8; ++dt) {
#pragma unroll
    for (int r = 0; r < 4; ++r) {
      int sr = q0 + w * 16 + quad * 4 + r;
      out[(size_t)(2 * sr + bp) * EMB + h * HD + dt * 16 + lq] = oacc[dt][r] / lrow[r];
    }
  }
}

extern "C" void kernel_launch(void* const* d_in, const int* in_sizes, int n_in,
                              void* d_out, int out_size, void* d_ws, size_t ws_size,
                              hipStream_t stream) {
  const float* val = (const float*)d_in[0];
  const float* bq  = (const float*)d_in[2];
  const float* bk  = (const float*)d_in[4];
  const float* bv  = (const float*)d_in[6];
  float* out = (float*)d_out;

  u16* valbf = (u16*)d_ws;                              // 8192*1024
  u16* Wbf   = valbf + (size_t)MROWS * EMB;             // 3*1024*1024
  u16* Qb    = Wbf + (size_t)3 * EMB * EMB;
  u16* Kb    = Qb + (size_t)MROWS * EMB;
  u16* VTg   = Kb + (size_t)MROWS * EMB;                // [b*8+h][128 d][4096 s]

  hipLaunchKernelGGL(cvt_f32_bf16, dim3(4096, 4), dim3(256), 0, stream,
                     val, (const float*)d_in[1], (const float*)d_in[3],
                     (const float*)d_in[5], valbf, Wbf);
  hipLaunchKernelGGL(qkv_gemm, dim3(24, 64), dim3(256), 0, stream,
                     valbf, Wbf, bq, bk, bv, Qb, Kb, VTg);
  hipLaunchKernelGGL(local_attn, dim3(16, 64), dim3(256), 0, stream,
                     Qb, Kb, VTg, out);
}